// Round 12
// baseline (233.569 us; speedup 1.0000x reference)
//
#include <hip/hip_runtime.h>
#include <hip/hip_bf16.h>

#define L_    4096
#define DIN   512
#define DOUT  256
#define NH    4
#define HD    64

typedef unsigned short u16;
typedef __attribute__((ext_vector_type(8))) short short8;   // 8 x bf16
typedef __attribute__((ext_vector_type(4))) float floatx4;  // MFMA C/D frag

__device__ __forceinline__ float bf2f(u16 u) {
  union { unsigned u32; float f; } v; v.u32 = ((unsigned)u) << 16; return v.f;
}
__device__ __forceinline__ u16 f2bf(float f) {  // RNE
  union { float f; unsigned u; } v; v.f = f;
  unsigned r = v.u + 0x7fff + ((v.u >> 16) & 1);
  return (u16)(r >> 16);
}
// HW packed fp32x2 -> bf16x2 (RNE)
__device__ __forceinline__ unsigned cvt2(float a, float b) {
  __hip_bfloat162 v = __float22bfloat162_rn(make_float2(a, b));
  return *reinterpret_cast<unsigned*>(&v);
}
__device__ __forceinline__ short8 pack8(const float* __restrict__ p) {
  float4 a = *(const float4*)p, b = *(const float4*)(p + 4);
  union { unsigned u[4]; short8 s; } r;
  r.u[0] = cvt2(a.x, a.y); r.u[1] = cvt2(a.z, a.w);
  r.u[2] = cvt2(b.x, b.y); r.u[3] = cvt2(b.z, b.w);
  return r.s;
}

// C/D map discovery (r10-verified contract); layout-map-free probes.
__device__ __forceinline__ void mfma_cdmap(int lane, int* rowm, int* colm) {
  const int c0 = lane & 15;
  union { u16 u[8]; short8 s; } a1, b1, a2, b2;
  const u16 one = f2bf(1.f), cid = f2bf((float)c0);
  #pragma unroll
  for (int j = 0; j < 8; ++j) { a1.u[j] = cid; b1.u[j] = one; a2.u[j] = one; b2.u[j] = cid; }
  floatx4 z = {0.f, 0.f, 0.f, 0.f};
  floatx4 dr = __builtin_amdgcn_mfma_f32_16x16x32_bf16(a1.s, b1.s, z, 0, 0, 0);
  floatx4 dc = __builtin_amdgcn_mfma_f32_16x16x32_bf16(a2.s, b2.s, z, 0, 0, 0);
  #pragma unroll
  for (int r = 0; r < 4; ++r) {
    rowm[r] = (int)(dr[r] * 0.03125f + 0.5f);
    colm[r] = (int)(dc[r] * 0.03125f + 0.5f);
  }
}

// ---------------------------------------------------------------------------
// K1: Wh = h @ W.T. Block 1024 = 16 waves (cg = wv&3 cols, kc = wv>>2 K-chunk).
// h staged to LDS bf16 (coalesced); reduction via LDS fp32 atomics (2 barriers);
// attn staged to LDS. Epilogue (verified): s1/s2 fp32 + WhT bf16 d-major.
// ---------------------------------------------------------------------------
__global__ __launch_bounds__(1024) void k1_wh(
    const float* __restrict__ h, const float* __restrict__ W,
    const float* __restrict__ attn,
    u16* __restrict__ WhT, float* __restrict__ s1g, float* __restrict__ s2g)
{
  const int i0 = blockIdx.x * 16;
  const int t = threadIdx.x;
  const int wv = t >> 6, lane = t & 63, q = lane >> 4, c0 = lane & 15;
  const int cg = wv & 3, kc = wv >> 2;
  int rowm[4], colm[4];
  mfma_cdmap(lane, rowm, colm);

  __shared__ u16  hT[16][DIN + 8];     // 16.6 KB, bf16 h-tile
  __shared__ float pA[16][DOUT + 8];   // 16.9 KB, fp32 accum
  __shared__ float attnL[NH * 128];    // 2 KB

  if (t < 512) attnL[t] = attn[t];
  {  // stage h-tile (coalesced): thread -> (row = t>>6, 8 cols at (t&63)*8)
    const int row = t >> 6, c8 = (t & 63) * 8;
    const float* hp = h + (size_t)(i0 + row) * DIN + c8;
    float4 a = *(const float4*)hp;
    float4 b = *(const float4*)(hp + 4);
    union { unsigned u[4]; int4 v; } pk;
    pk.u[0] = cvt2(a.x, a.y); pk.u[1] = cvt2(a.z, a.w);
    pk.u[2] = cvt2(b.x, b.y); pk.u[3] = cvt2(b.z, b.w);
    *(int4*)&hT[row][c8] = pk.v;
  }
  for (int i = t; i < 16 * (DOUT + 8); i += 1024) ((float*)pA)[i] = 0.f;
  __syncthreads();

  floatx4 acc[4] = {};
  #pragma unroll
  for (int ktl = 0; ktl < 4; ++ktl) {
    const int kb = kc * 128 + ktl * 32 + q * 8;
    short8 af = *(const short8*)&hT[c0][kb];         // A[m=c0][k] via LDS
    #pragma unroll
    for (int nt = 0; nt < 4; ++nt) {
      const int col = cg * 64 + nt * 16 + c0;        // B[k][n=c0]
      short8 bf = pack8(W + (size_t)col * DIN + kb);
      acc[nt] = __builtin_amdgcn_mfma_f32_16x16x32_bf16(af, bf, acc[nt], 0, 0, 0);
    }
  }
  #pragma unroll
  for (int nt = 0; nt < 4; ++nt)
    #pragma unroll
    for (int r = 0; r < 4; ++r)
      atomicAdd(&pA[rowm[r]][cg * 64 + nt * 16 + colm[r]], acc[nt][r]);
  __syncthreads();

  if (t < 64) {  // 16 rows x 4 heads -> s1, s2 (all-LDS inputs)
    const int r = t & 15, hh = t >> 4;
    float s1 = 0.f, s2 = 0.f;
    for (int d = 0; d < HD; ++d) {
      float v = pA[r][hh * 64 + d];
      s1 += v * attnL[hh * 128 + d];
      s2 += v * attnL[hh * 128 + 64 + d];
    }
    s1g[hh * L_ + i0 + r] = s1;
    s2g[hh * L_ + i0 + r] = s2;
  }

  if (t < 256) {  // WhT store (d-major [DOUT][L]): thread t = column c
    const int c = t;
    union { unsigned u[4]; int4 v; } p0, p1;
    p0.u[0] = cvt2(pA[0][c],  pA[1][c]);  p0.u[1] = cvt2(pA[2][c],  pA[3][c]);
    p0.u[2] = cvt2(pA[4][c],  pA[5][c]);  p0.u[3] = cvt2(pA[6][c],  pA[7][c]);
    p1.u[0] = cvt2(pA[8][c],  pA[9][c]);  p1.u[1] = cvt2(pA[10][c], pA[11][c]);
    p1.u[2] = cvt2(pA[12][c], pA[13][c]); p1.u[3] = cvt2(pA[14][c], pA[15][c]);
    *(int4*)(WhT + (size_t)c * L_ + i0)     = p0.v;
    *(int4*)(WhT + (size_t)c * L_ + i0 + 8) = p1.v;
  }
}

// ---------------------------------------------------------------------------
// K2: masked softmax + PV + fused projection. Block 1024 = 16 waves
// (hd = wv&3, jc = wv>>2). r11-verified structure + explicit depth-2
// software pipeline in the hot loop; clamps dropped (r6-verified math).
// ---------------------------------------------------------------------------
__global__ __launch_bounds__(1024) void k2_attn(
    const int* __restrict__ A, const u16* __restrict__ WhT,
    const float* __restrict__ s1g, const float* __restrict__ s2g,
    const float* __restrict__ out_w, const float* __restrict__ out_b,
    float* __restrict__ out)
{
  const int i0 = blockIdx.x * 16;
  const int t = threadIdx.x;
  const int wv = t >> 6, lane = t & 63, q = lane >> 4, c0 = lane & 15;
  const int hd = wv & 3, jc = wv >> 2;
  int rowm[4], colm[4];
  mfma_cdmap(lane, rowm, colm);

  __shared__ float pA[NH][16][HD + 4];
  __shared__ float pB[NH][16][HD + 4];
  __shared__ float dden[NH][4][16];
  __shared__ float rcpS[NH][16];
  __shared__ u16  CnL[16][DOUT + 8];

  const float s1v = s1g[hd * L_ + i0 + c0];
  const int* Arow = A + (size_t)(i0 + c0) * L_;
  const float* s2h = s2g + (size_t)hd * L_;
  const u16* WhTh = WhT + (size_t)(hd * 64 + c0) * L_;

  floatx4 acc[4] = {};
  float dpart = 0.f;
  const int jbase = jc * 1024;

  // ---- software-pipelined hot loop (depth 2) ----
  int kb = jbase + q * 8;
  float4 sa = *(const float4*)(s2h + kb);
  float4 sb = *(const float4*)(s2h + kb + 4);
  int4   m0 = *(const int4*)(Arow + kb);
  int4   m1 = *(const int4*)(Arow + kb + 4);
  short8 w0 = *(const short8*)(WhTh + kb);
  short8 w1 = *(const short8*)(WhTh + (size_t)16 * L_ + kb);
  short8 w2 = *(const short8*)(WhTh + (size_t)32 * L_ + kb);
  short8 w3 = *(const short8*)(WhTh + (size_t)48 * L_ + kb);

  #pragma unroll 2
  for (int kt = 0; kt < 32; ++kt) {
    float4 csa = sa, csb = sb;
    int4   cm0 = m0, cm1 = m1;
    short8 v0 = w0, v1 = w1, v2 = w2, v3 = w3;
    if (kt < 31) {  // prefetch iter kt+1
      const int nkb = jbase + (kt + 1) * 32 + q * 8;
      sa = *(const float4*)(s2h + nkb);
      sb = *(const float4*)(s2h + nkb + 4);
      m0 = *(const int4*)(Arow + nkb);
      m1 = *(const int4*)(Arow + nkb + 4);
      w0 = *(const short8*)(WhTh + nkb);
      w1 = *(const short8*)(WhTh + (size_t)16 * L_ + nkb);
      w2 = *(const short8*)(WhTh + (size_t)32 * L_ + nkb);
      w3 = *(const short8*)(WhTh + (size_t)48 * L_ + nkb);
    }
    const int   mk[8] = {cm0.x, cm0.y, cm0.z, cm0.w, cm1.x, cm1.y, cm1.z, cm1.w};
    const float sv[8] = {csa.x, csa.y, csa.z, csa.w, csb.x, csb.y, csb.z, csb.w};
    float ex[8];
    #pragma unroll
    for (int jj = 0; jj < 8; ++jj) {
      float e = s1v + sv[jj];
      e = fmaxf(e, 0.2f * e);                       // leaky_relu (bounded; no clamp)
      float x = __expf(e);
      ex[jj] = (mk[jj] > 0) ? x : 0.f;              // mask = (A > 0)
      dpart += ex[jj];
    }
    union { unsigned u[4]; short8 s; } pf;          // P A-frag [m=c0][k=j]
    pf.u[0] = cvt2(ex[0], ex[1]); pf.u[1] = cvt2(ex[2], ex[3]);
    pf.u[2] = cvt2(ex[4], ex[5]); pf.u[3] = cvt2(ex[6], ex[7]);
    acc[0] = __builtin_amdgcn_mfma_f32_16x16x32_bf16(pf.s, v0, acc[0], 0, 0, 0);
    acc[1] = __builtin_amdgcn_mfma_f32_16x16x32_bf16(pf.s, v1, acc[1], 0, 0, 0);
    acc[2] = __builtin_amdgcn_mfma_f32_16x16x32_bf16(pf.s, v2, acc[2], 0, 0, 0);
    acc[3] = __builtin_amdgcn_mfma_f32_16x16x32_bf16(pf.s, v3, acc[3], 0, 0, 0);
  }

  // partial denom of row c0 over this j-chunk
  dpart += __shfl_xor(dpart, 16, 64);
  dpart += __shfl_xor(dpart, 32, 64);
  if (lane < 16) dden[hd][jc][lane] = dpart;

  auto writeT = [&](float (*P)[HD + 4]) {
    #pragma unroll
    for (int nt = 0; nt < 4; ++nt)
      #pragma unroll
      for (int r = 0; r < 4; ++r)
        P[rowm[r]][nt * 16 + colm[r]] = acc[nt][r];
  };
  auto addB2A = [&]() {   // pA += pB, 4x16x64, 4 elems/thread
    const int h2 = t >> 8, rem = t & 255, row = rem >> 4, d4 = (rem & 15) * 4;
    float4* a = (float4*)&pA[h2][row][d4];
    float4 bv = *(float4*)&pB[h2][row][d4];
    float4 av = *a;
    av.x += bv.x; av.y += bv.y; av.z += bv.z; av.w += bv.w;
    *a = av;
  };

  if (jc == 0) writeT(pA[hd]);
  if (jc == 1) writeT(pB[hd]);
  __syncthreads();
  if (t < 64) {   // full-row reciprocal
    const int hh = t >> 4, r = t & 15;
    float den = dden[hh][0][r] + dden[hh][1][r] + dden[hh][2][r] + dden[hh][3][r];
    rcpS[hh][r] = (den > 0.f) ? (1.f / den) : 0.f;  // empty row -> out = bias
  }
  addB2A();
  __syncthreads();
  if (jc == 2) writeT(pB[hd]);
  __syncthreads();
  addB2A();
  __syncthreads();
  if (jc == 3) writeT(pB[hd]);
  __syncthreads();
  addB2A();
  __syncthreads();

  {  // Cn (bf16): 16x256, 4 elems/thread
    const int row = t >> 6, c4 = (t & 63) * 4;
    #pragma unroll
    for (int x = 0; x < 4; ++x) {
      const int col = c4 + x;
      const int hh = col >> 6, d = col & 63;
      CnL[row][col] = f2bf(pA[hh][row][d] * rcpS[hh][row]);
    }
  }
  __syncthreads();

  if (wv < 4) {  // projection: Out2(16x256) = Cn @ out_w.T; wave cg -> 64 cols
    const int cg = wv;
    floatx4 o[4] = {};
    #pragma unroll
    for (int kt = 0; kt < DOUT / 32; ++kt) {
      const int kb2 = kt * 32 + q * 8;
      short8 afr = *(const short8*)(&CnL[c0][kb2]);  // A[m=c0][k]
      #pragma unroll
      for (int nt = 0; nt < 4; ++nt) {
        const int col = cg * 64 + nt * 16 + c0;      // B[k][n=c0]
        short8 bfo = pack8(out_w + (size_t)col * DOUT + kb2);
        o[nt] = __builtin_amdgcn_mfma_f32_16x16x32_bf16(afr, bfo, o[nt], 0, 0, 0);
      }
    }
    #pragma unroll
    for (int nt = 0; nt < 4; ++nt)
      #pragma unroll
      for (int r = 0; r < 4; ++r) {
        const int col = cg * 64 + nt * 16 + colm[r];
        out[(size_t)(i0 + rowm[r]) * DOUT + col] = o[nt][r] + out_b[col];
      }
  }
}

// ---------------------------------------------------------------------------
extern "C" void kernel_launch(void* const* d_in, const int* in_sizes, int n_in,
                              void* d_out, int out_size, void* d_ws, size_t ws_size,
                              hipStream_t stream) {
  const float* h     = (const float*)d_in[0];   // (4096, 512) fp32
  const int*   A     = (const int*)d_in[1];     // (4096, 4096) int32
  const float* W     = (const float*)d_in[2];   // (256, 512) fp32
  const float* attn  = (const float*)d_in[3];   // (4, 128) fp32
  const float* out_w = (const float*)d_in[4];   // (256, 256) fp32
  const float* out_b = (const float*)d_in[5];   // (256,) fp32
  float* outp = (float*)d_out;                  // (4096, 256) fp32

  // ws: WhT bf16 [256][4096] (2 MB) | s1 f32 [4][4096] | s2 f32 [4][4096]
  u16*   WhT = (u16*)d_ws;
  float* s1g = (float*)((char*)d_ws + (size_t)DOUT * L_ * 2);
  float* s2g = s1g + NH * L_;

  hipLaunchKernelGGL(k1_wh, dim3(L_ / 16), dim3(1024), 0, stream,
                     h, W, attn, WhT, s1g, s2g);
  hipLaunchKernelGGL(k2_attn, dim3(L_ / 16), dim3(1024), 0, stream,
                     A, WhT, s1g, s2g, out_w, out_b, outp);
}

// Round 13
// 165.002 us; speedup vs baseline: 1.4156x; 1.4156x over previous
//
#include <hip/hip_runtime.h>
#include <hip/hip_bf16.h>

#define L_    4096
#define DIN   512
#define DOUT  256
#define NH    4
#define HD    64
#define JW    128                      // L_/32 j-blocks (and A-bit words per row)
// proven ws floor: WhTf 2MB + s1/s2 128KB; Abits needs +2MB
#define WS_BITS_NEEDED (2097152u + 131072u + 2097152u)

typedef unsigned short u16;
typedef __attribute__((ext_vector_type(8))) short short8;   // 8 x bf16
typedef __attribute__((ext_vector_type(4))) float floatx4;  // MFMA C/D frag

__device__ __forceinline__ float bf2f(u16 u) {
  union { unsigned u32; float f; } v; v.u32 = ((unsigned)u) << 16; return v.f;
}
__device__ __forceinline__ u16 f2bf(float f) {  // RNE
  union { float f; unsigned u; } v; v.f = f;
  unsigned r = v.u + 0x7fff + ((v.u >> 16) & 1);
  return (u16)(r >> 16);
}
__device__ __forceinline__ unsigned cvt2(float a, float b) {  // HW pack fp32x2->bf16x2
  __hip_bfloat162 v = __float22bfloat162_rn(make_float2(a, b));
  return *reinterpret_cast<unsigned*>(&v);
}
__device__ __forceinline__ short8 pack8(const float* __restrict__ p) {
  float4 a = *(const float4*)p, b = *(const float4*)(p + 4);
  union { unsigned u[4]; short8 s; } r;
  r.u[0] = cvt2(a.x, a.y); r.u[1] = cvt2(a.z, a.w);
  r.u[2] = cvt2(b.x, b.y); r.u[3] = cvt2(b.z, b.w);
  return r.s;
}

// C/D map discovery (r10-verified contract); layout-map-free probes.
__device__ __forceinline__ void mfma_cdmap(int lane, int* rowm, int* colm) {
  const int c0 = lane & 15;
  union { u16 u[8]; short8 s; } a1, b1, a2, b2;
  const u16 one = f2bf(1.f), cid = f2bf((float)c0);
  #pragma unroll
  for (int j = 0; j < 8; ++j) { a1.u[j] = cid; b1.u[j] = one; a2.u[j] = one; b2.u[j] = cid; }
  floatx4 z = {0.f, 0.f, 0.f, 0.f};
  floatx4 dr = __builtin_amdgcn_mfma_f32_16x16x32_bf16(a1.s, b1.s, z, 0, 0, 0);
  floatx4 dc = __builtin_amdgcn_mfma_f32_16x16x32_bf16(a2.s, b2.s, z, 0, 0, 0);
  #pragma unroll
  for (int r = 0; r < 4; ++r) {
    rowm[r] = (int)(dr[r] * 0.03125f + 0.5f);
    colm[r] = (int)(dc[r] * 0.03125f + 0.5f);
  }
}

// ---------------------------------------------------------------------------
// k0a: A (int32 4096x4096) -> bitmask (2 MB). Thread g packs 32 ints -> 1 word.
// Coalesced: each thread reads 128B contiguous. bit b of word wi = (A[row][wi*32+b] > 0).
// ---------------------------------------------------------------------------
__global__ __launch_bounds__(256) void k0a_bits(const int* __restrict__ A,
                                               unsigned* __restrict__ Abits) {
  const int g = blockIdx.x * 256 + threadIdx.x;
  const int row = g >> 7, wi = g & 127;
  const int* p = A + (size_t)row * L_ + wi * 32;
  unsigned bits = 0u;
  #pragma unroll
  for (int wd = 0; wd < 8; ++wd) {
    int4 v = *(const int4*)(p + wd * 4);
    bits |= (v.x > 0 ? 1u : 0u) << (wd * 4 + 0);
    bits |= (v.y > 0 ? 1u : 0u) << (wd * 4 + 1);
    bits |= (v.z > 0 ? 1u : 0u) << (wd * 4 + 2);
    bits |= (v.w > 0 ? 1u : 0u) << (wd * 4 + 3);
  }
  Abits[(size_t)row * JW + wi] = bits;
}

// ---------------------------------------------------------------------------
// k0b: W (fp32 256x512) -> Wf (bf16, k1-fragment chunk order, 256 KB in d_out).
// chunk(cg,nt,kblock) of 512 bf16; element (lane=q*16+c0, jj) =
//   W[cg*64+nt*16+c0][kblock*32 + q*8 + jj].
// ---------------------------------------------------------------------------
__global__ __launch_bounds__(256) void k0b_wf(const float* __restrict__ W,
                                              u16* __restrict__ Wf) {
  const int g = blockIdx.x * 256 + threadIdx.x;   // 4096 threads
  const int col = g >> 4, kblock = g & 15;
  const int cg = col >> 6, nt = (col >> 4) & 3, c0 = col & 15;
  const float* src = W + (size_t)col * DIN + kblock * 32;
  u16* dst = Wf + ((size_t)(cg * 4 + nt) * 16 + kblock) * 512 + c0 * 8;
  #pragma unroll
  for (int q = 0; q < 4; ++q) {
    short8 v = pack8(src + q * 8);
    *(short8*)(dst + q * 128) = v;     // (q*16+c0)*8 = q*128 + c0*8
  }
}

// ---------------------------------------------------------------------------
// K1: Wh = h @ W.T. Block 1024 = 16 waves (cg = wv&3, kc = wv>>2).
// h staged to LDS bf16 (coalesced); W read coalesced from Wf; phased 2-plane
// LDS reduction (r11-measured best). Outputs: s1/s2 fp32 + WhTf (bf16,
// k2-fragment chunk order: chunk(hd,nt,jblock), element (lane,jj) =
//   Wh[jblock*32 + (lane>>4)*8 + jj][hd*64 + nt*16 + (lane&15)]).
// ---------------------------------------------------------------------------
__global__ __launch_bounds__(1024) void k1_wh(
    const float* __restrict__ h, const u16* __restrict__ Wf,
    const float* __restrict__ attn,
    u16* __restrict__ WhTf, float* __restrict__ s1g, float* __restrict__ s2g)
{
  const int i0 = blockIdx.x * 16;
  const int t = threadIdx.x;
  const int wv = t >> 6, lane = t & 63, q = lane >> 4, c0 = lane & 15;
  const int cg = wv & 3, kc = wv >> 2;
  int rowm[4], colm[4];
  mfma_cdmap(lane, rowm, colm);

  __shared__ u16  hT[16][DIN + 8];     // bf16 h-tile
  __shared__ float pA[16][DOUT + 8];
  __shared__ float pB[16][DOUT + 8];
  __shared__ float attnL[NH * 128];

  if (t < 512) attnL[t] = attn[t];
  {  // stage h-tile coalesced: (row = t>>6, 8 cols at (t&63)*8)
    const int row = t >> 6, c8 = (t & 63) * 8;
    const float* hp = h + (size_t)(i0 + row) * DIN + c8;
    float4 a = *(const float4*)hp;
    float4 b = *(const float4*)(hp + 4);
    union { unsigned u[4]; int4 v; } pk;
    pk.u[0] = cvt2(a.x, a.y); pk.u[1] = cvt2(a.z, a.w);
    pk.u[2] = cvt2(b.x, b.y); pk.u[3] = cvt2(b.z, b.w);
    *(int4*)&hT[row][c8] = pk.v;
  }
  __syncthreads();

  floatx4 acc[4] = {};
  #pragma unroll
  for (int ktl = 0; ktl < 4; ++ktl) {
    const int kb = kc * 128 + ktl * 32 + q * 8;
    short8 af = *(const short8*)&hT[c0][kb];        // A[m=c0][k]
    #pragma unroll
    for (int nt = 0; nt < 4; ++nt) {                // coalesced Wf chunk load
      short8 bf = *(const short8*)(Wf + ((size_t)(cg * 4 + nt) * 16 + kc * 4 + ktl) * 512 + lane * 8);
      acc[nt] = __builtin_amdgcn_mfma_f32_16x16x32_bf16(af, bf, acc[nt], 0, 0, 0);
    }
  }

  auto writeT = [&](float (*P)[DOUT + 8]) {
    #pragma unroll
    for (int nt = 0; nt < 4; ++nt)
      #pragma unroll
      for (int r = 0; r < 4; ++r)
        P[rowm[r]][cg * 64 + nt * 16 + colm[r]] = acc[nt][r];
  };
  auto addB2A = [&]() {
    const int row = t >> 6, c4 = (t & 63) * 4;
    float4* a = (float4*)&pA[row][c4];
    float4 bv = *(float4*)&pB[row][c4];
    float4 av = *a;
    av.x += bv.x; av.y += bv.y; av.z += bv.z; av.w += bv.w;
    *a = av;
  };

  if (kc == 0) writeT(pA);
  if (kc == 1) writeT(pB);
  __syncthreads();
  addB2A();
  __syncthreads();
  if (kc == 2) writeT(pB);
  __syncthreads();
  addB2A();
  __syncthreads();
  if (kc == 3) writeT(pB);
  __syncthreads();
  addB2A();
  __syncthreads();

  if (t < 64) {  // s1/s2
    const int r = t & 15, hh = t >> 4;
    float s1 = 0.f, s2 = 0.f;
    for (int d = 0; d < HD; ++d) {
      float v = pA[r][hh * 64 + d];
      s1 += v * attnL[hh * 128 + d];
      s2 += v * attnL[hh * 128 + 64 + d];
    }
    s1g[hh * L_ + i0 + r] = s1;
    s2g[hh * L_ + i0 + r] = s2;
  }

  if (t < 256) {  // WhTf store: thread t = d; two 16B writes (rows i0..i0+15)
    const int d = t;
    const int hd = d >> 6, nt = (d >> 4) & 3, dc0 = d & 15;
    const int jblock = i0 >> 5, qbase = (i0 & 31) >> 3;
    u16* base = WhTf + ((size_t)(hd * 4 + nt) * JW + jblock) * 512 + dc0 * 8;
    #pragma unroll
    for (int jh = 0; jh < 2; ++jh) {
      const int i = jh * 8;            // local row
      union { unsigned u[4]; int4 v; } pk;
      pk.u[0] = cvt2(pA[i + 0][d], pA[i + 1][d]);
      pk.u[1] = cvt2(pA[i + 2][d], pA[i + 3][d]);
      pk.u[2] = cvt2(pA[i + 4][d], pA[i + 5][d]);
      pk.u[3] = cvt2(pA[i + 6][d], pA[i + 7][d]);
      *(int4*)(base + (qbase + jh) * 128) = pk.v;
    }
  }
}

// ---------------------------------------------------------------------------
// K2: masked softmax + PV + fused projection. Block 1024 = 16 waves
// (hd = wv&3, jc = wv>>2). All hot-loop loads coalesced (WhTf chunks) or
// broadcast (s2) or line-reused (Abits / raw A fallback).
// ---------------------------------------------------------------------------
__global__ __launch_bounds__(1024) void k2_attn(
    const int* __restrict__ A, const unsigned* __restrict__ Abits, int useBits,
    const u16* __restrict__ WhTf,
    const float* __restrict__ s1g, const float* __restrict__ s2g,
    const float* __restrict__ out_w, const float* __restrict__ out_b,
    float* __restrict__ out)
{
  const int i0 = blockIdx.x * 16;
  const int t = threadIdx.x;
  const int wv = t >> 6, lane = t & 63, q = lane >> 4, c0 = lane & 15;
  const int hd = wv & 3, jc = wv >> 2;
  int rowm[4], colm[4];
  mfma_cdmap(lane, rowm, colm);

  __shared__ float pA[NH][16][HD + 4];
  __shared__ float pB[NH][16][HD + 4];
  __shared__ float dden[NH][4][16];
  __shared__ float rcpS[NH][16];
  __shared__ u16  CnL[16][DOUT + 8];

  const float s1v = s1g[hd * L_ + i0 + c0];
  const int* Arow = A + (size_t)(i0 + c0) * L_;
  const unsigned* Abrow = Abits + (size_t)(i0 + c0) * JW + jc * 32;
  const float* s2h = s2g + (size_t)hd * L_;
  const u16* Wc = WhTf + (size_t)(hd * 4) * JW * 512 + (size_t)(jc * 32) * 512 + lane * 8;

  floatx4 acc[4] = {};
  float dpart = 0.f;
  const int jbase = jc * 1024;

  for (int kt = 0; kt < 32; ++kt) {
    const int kb = jbase + kt * 32 + q * 8;
    float4 sa = *(const float4*)(s2h + kb);
    float4 sb = *(const float4*)(s2h + kb + 4);
    const float sv[8] = {sa.x, sa.y, sa.z, sa.w, sb.x, sb.y, sb.z, sb.w};
    unsigned mbits;
    if (useBits) {
      mbits = (Abrow[kt] >> (q * 8)) & 0xffu;       // 8 mask bits for this lane
    } else {
      int4 m0 = *(const int4*)(Arow + kb);
      int4 m1 = *(const int4*)(Arow + kb + 4);
      mbits =  (m0.x > 0 ? 1u : 0u)       | (m0.y > 0 ? 2u : 0u)
            | (m0.z > 0 ? 4u : 0u)        | (m0.w > 0 ? 8u : 0u)
            | (m1.x > 0 ? 16u : 0u)       | (m1.y > 0 ? 32u : 0u)
            | (m1.z > 0 ? 64u : 0u)       | (m1.w > 0 ? 128u : 0u);
    }
    float ex[8];
    #pragma unroll
    for (int jj = 0; jj < 8; ++jj) {
      float e = s1v + sv[jj];
      e = fmaxf(e, 0.2f * e);                       // leaky_relu 0.2
      float x = __expf(e);
      ex[jj] = ((mbits >> jj) & 1u) ? x : 0.f;      // mask = (A > 0)
      dpart += ex[jj];
    }
    union { unsigned u[4]; short8 s; } pf;          // P A-frag [m=c0][k=j]
    pf.u[0] = cvt2(ex[0], ex[1]); pf.u[1] = cvt2(ex[2], ex[3]);
    pf.u[2] = cvt2(ex[4], ex[5]); pf.u[3] = cvt2(ex[6], ex[7]);
    #pragma unroll
    for (int nt = 0; nt < 4; ++nt) {                // coalesced 1KB chunk loads
      short8 bfr = *(const short8*)(Wc + ((size_t)nt * JW + kt) * 512);
      acc[nt] = __builtin_amdgcn_mfma_f32_16x16x32_bf16(pf.s, bfr, acc[nt], 0, 0, 0);
    }
  }

  // partial denom of row c0 over this j-chunk
  dpart += __shfl_xor(dpart, 16, 64);
  dpart += __shfl_xor(dpart, 32, 64);
  if (lane < 16) dden[hd][jc][lane] = dpart;

  auto writeT = [&](float (*P)[HD + 4]) {
    #pragma unroll
    for (int nt = 0; nt < 4; ++nt)
      #pragma unroll
      for (int r = 0; r < 4; ++r)
        P[rowm[r]][nt * 16 + colm[r]] = acc[nt][r];
  };
  auto addB2A = [&]() {
    const int h2 = t >> 8, rem = t & 255, row = rem >> 4, d4 = (rem & 15) * 4;
    float4* a = (float4*)&pA[h2][row][d4];
    float4 bv = *(float4*)&pB[h2][row][d4];
    float4 av = *a;
    av.x += bv.x; av.y += bv.y; av.z += bv.z; av.w += bv.w;
    *a = av;
  };

  if (jc == 0) writeT(pA[hd]);
  if (jc == 1) writeT(pB[hd]);
  __syncthreads();
  if (t < 64) {
    const int hh = t >> 4, r = t & 15;
    float den = dden[hh][0][r] + dden[hh][1][r] + dden[hh][2][r] + dden[hh][3][r];
    rcpS[hh][r] = (den > 0.f) ? (1.f / den) : 0.f;  // empty row -> out = bias
  }
  addB2A();
  __syncthreads();
  if (jc == 2) writeT(pB[hd]);
  __syncthreads();
  addB2A();
  __syncthreads();
  if (jc == 3) writeT(pB[hd]);
  __syncthreads();
  addB2A();
  __syncthreads();

  {  // Cn (bf16)
    const int row = t >> 6, c4 = (t & 63) * 4;
    #pragma unroll
    for (int x = 0; x < 4; ++x) {
      const int col = c4 + x;
      const int hh = col >> 6, d = col & 63;
      CnL[row][col] = f2bf(pA[hh][row][d] * rcpS[hh][row]);
    }
  }
  __syncthreads();

  if (wv < 4) {  // projection: Out2(16x256) = Cn @ out_w.T
    const int cg = wv;
    floatx4 o[4] = {};
    #pragma unroll
    for (int kt = 0; kt < DOUT / 32; ++kt) {
      const int kb2 = kt * 32 + q * 8;
      short8 afr = *(const short8*)(&CnL[c0][kb2]);
      #pragma unroll
      for (int nt = 0; nt < 4; ++nt) {
        const int col = cg * 64 + nt * 16 + c0;
        short8 bfo = pack8(out_w + (size_t)col * DOUT + kb2);
        o[nt] = __builtin_amdgcn_mfma_f32_16x16x32_bf16(afr, bfo, o[nt], 0, 0, 0);
      }
    }
    #pragma unroll
    for (int nt = 0; nt < 4; ++nt)
      #pragma unroll
      for (int r = 0; r < 4; ++r) {
        const int col = cg * 64 + nt * 16 + colm[r];
        out[(size_t)(i0 + rowm[r]) * DOUT + col] = o[nt][r] + out_b[col];
      }
  }
}

// ---------------------------------------------------------------------------
extern "C" void kernel_launch(void* const* d_in, const int* in_sizes, int n_in,
                              void* d_out, int out_size, void* d_ws, size_t ws_size,
                              hipStream_t stream) {
  const float* h     = (const float*)d_in[0];   // (4096, 512) fp32
  const int*   A     = (const int*)d_in[1];     // (4096, 4096) int32
  const float* W     = (const float*)d_in[2];   // (256, 512) fp32
  const float* attn  = (const float*)d_in[3];   // (4, 128) fp32
  const float* out_w = (const float*)d_in[4];   // (256, 256) fp32
  const float* out_b = (const float*)d_in[5];   // (256,) fp32
  float* outp = (float*)d_out;                  // (4096, 256) fp32

  // ws: WhTf bf16 (2 MB) | s1 f32 | s2 f32 | [Abits 2 MB if room]
  u16*      WhTf  = (u16*)d_ws;
  float*    s1g   = (float*)((char*)d_ws + (size_t)DOUT * L_ * 2);
  float*    s2g   = s1g + NH * L_;
  unsigned* Abits = (unsigned*)((char*)d_ws + 2097152u + 131072u);
  const int useBits = (ws_size >= (size_t)WS_BITS_NEEDED) ? 1 : 0;
  // Wf lives in d_out (k0b -> k1 -> k2 serialize; k2 overwrites d_out last)
  u16* Wf = (u16*)d_out;

  if (useBits)
    hipLaunchKernelGGL(k0a_bits, dim3((L_ * JW) / 256), dim3(256), 0, stream, A, Abits);
  hipLaunchKernelGGL(k0b_wf, dim3(16), dim3(256), 0, stream, W, Wf);
  hipLaunchKernelGGL(k1_wh, dim3(L_ / 16), dim3(1024), 0, stream,
                     h, Wf, attn, WhTf, s1g, s2g);
  hipLaunchKernelGGL(k2_attn, dim3(L_ / 16), dim3(1024), 0, stream,
                     A, Abits, useBits, WhTf, s1g, s2g, out_w, out_b, outp);
}

// Round 14
// 157.927 us; speedup vs baseline: 1.4790x; 1.0448x over previous
//
#include <hip/hip_runtime.h>
#include <hip/hip_bf16.h>

#define L_    4096
#define DIN   512
#define DOUT  256
#define NH    4
#define HD    64
#define JW    128                      // L_/32 j-words per row

typedef unsigned short u16;
typedef __attribute__((ext_vector_type(8))) short short8;   // 8 x bf16
typedef __attribute__((ext_vector_type(4))) float floatx4;  // MFMA C/D frag

__device__ __forceinline__ float bf2f(u16 u) {
  union { unsigned u32; float f; } v; v.u32 = ((unsigned)u) << 16; return v.f;
}
__device__ __forceinline__ u16 f2bf(float f) {  // RNE
  union { float f; unsigned u; } v; v.f = f;
  unsigned r = v.u + 0x7fff + ((v.u >> 16) & 1);
  return (u16)(r >> 16);
}
__device__ __forceinline__ unsigned cvt2(float a, float b) {  // HW pack fp32x2->bf16x2
  __hip_bfloat162 v = __float22bfloat162_rn(make_float2(a, b));
  return *reinterpret_cast<unsigned*>(&v);
}
__device__ __forceinline__ short8 pack8(const float* __restrict__ p) {
  float4 a = *(const float4*)p, b = *(const float4*)(p + 4);
  union { unsigned u[4]; short8 s; } r;
  r.u[0] = cvt2(a.x, a.y); r.u[1] = cvt2(a.z, a.w);
  r.u[2] = cvt2(b.x, b.y); r.u[3] = cvt2(b.z, b.w);
  return r.s;
}

// C/D map discovery (r10-verified contract); layout-map-free probes.
__device__ __forceinline__ void mfma_cdmap(int lane, int* rowm, int* colm) {
  const int c0 = lane & 15;
  union { u16 u[8]; short8 s; } a1, b1, a2, b2;
  const u16 one = f2bf(1.f), cid = f2bf((float)c0);
  #pragma unroll
  for (int j = 0; j < 8; ++j) { a1.u[j] = cid; b1.u[j] = one; a2.u[j] = one; b2.u[j] = cid; }
  floatx4 z = {0.f, 0.f, 0.f, 0.f};
  floatx4 dr = __builtin_amdgcn_mfma_f32_16x16x32_bf16(a1.s, b1.s, z, 0, 0, 0);
  floatx4 dc = __builtin_amdgcn_mfma_f32_16x16x32_bf16(a2.s, b2.s, z, 0, 0, 0);
  #pragma unroll
  for (int r = 0; r < 4; ++r) {
    rowm[r] = (int)(dr[r] * 0.03125f + 0.5f);
    colm[r] = (int)(dc[r] * 0.03125f + 0.5f);
  }
}

// ---------------------------------------------------------------------------
// k0b: W (fp32 256x512) -> Wf (bf16, k1-fragment chunk order, 256 KB in d_out).
// ---------------------------------------------------------------------------
__global__ __launch_bounds__(256) void k0b_wf(const float* __restrict__ W,
                                              u16* __restrict__ Wf) {
  const int g = blockIdx.x * 256 + threadIdx.x;   // 4096 threads
  const int col = g >> 4, kblock = g & 15;
  const int cg = col >> 6, nt = (col >> 4) & 3, c0 = col & 15;
  const float* src = W + (size_t)col * DIN + kblock * 32;
  u16* dst = Wf + ((size_t)(cg * 4 + nt) * 16 + kblock) * 512 + c0 * 8;
  #pragma unroll
  for (int q = 0; q < 4; ++q) {
    short8 v = pack8(src + q * 8);
    *(short8*)(dst + q * 128) = v;     // (q*16+c0)*8 = q*128 + c0*8
  }
}

// ---------------------------------------------------------------------------
// K1: Wh = h @ W.T. Block 1024 = 16 waves (cg = wv&3, kc = wv>>2).
// (r13-verified) h staged to LDS bf16; W coalesced from Wf; phased 2-plane
// reduction. Outputs s1/s2 fp32 + WhTf (bf16, k2-fragment chunk order).
// ---------------------------------------------------------------------------
__global__ __launch_bounds__(1024) void k1_wh(
    const float* __restrict__ h, const u16* __restrict__ Wf,
    const float* __restrict__ attn,
    u16* __restrict__ WhTf, float* __restrict__ s1g, float* __restrict__ s2g)
{
  const int i0 = blockIdx.x * 16;
  const int t = threadIdx.x;
  const int wv = t >> 6, lane = t & 63, q = lane >> 4, c0 = lane & 15;
  const int cg = wv & 3, kc = wv >> 2;
  int rowm[4], colm[4];
  mfma_cdmap(lane, rowm, colm);

  __shared__ u16  hT[16][DIN + 8];
  __shared__ float pA[16][DOUT + 8];
  __shared__ float pB[16][DOUT + 8];
  __shared__ float attnL[NH * 128];

  if (t < 512) attnL[t] = attn[t];
  {  // stage h-tile coalesced
    const int row = t >> 6, c8 = (t & 63) * 8;
    const float* hp = h + (size_t)(i0 + row) * DIN + c8;
    float4 a = *(const float4*)hp;
    float4 b = *(const float4*)(hp + 4);
    union { unsigned u[4]; int4 v; } pk;
    pk.u[0] = cvt2(a.x, a.y); pk.u[1] = cvt2(a.z, a.w);
    pk.u[2] = cvt2(b.x, b.y); pk.u[3] = cvt2(b.z, b.w);
    *(int4*)&hT[row][c8] = pk.v;
  }
  __syncthreads();

  floatx4 acc[4] = {};
  #pragma unroll
  for (int ktl = 0; ktl < 4; ++ktl) {
    const int kb = kc * 128 + ktl * 32 + q * 8;
    short8 af = *(const short8*)&hT[c0][kb];        // A[m=c0][k]
    #pragma unroll
    for (int nt = 0; nt < 4; ++nt) {
      short8 bf = *(const short8*)(Wf + ((size_t)(cg * 4 + nt) * 16 + kc * 4 + ktl) * 512 + lane * 8);
      acc[nt] = __builtin_amdgcn_mfma_f32_16x16x32_bf16(af, bf, acc[nt], 0, 0, 0);
    }
  }

  auto writeT = [&](float (*P)[DOUT + 8]) {
    #pragma unroll
    for (int nt = 0; nt < 4; ++nt)
      #pragma unroll
      for (int r = 0; r < 4; ++r)
        P[rowm[r]][cg * 64 + nt * 16 + colm[r]] = acc[nt][r];
  };
  auto addB2A = [&]() {
    const int row = t >> 6, c4 = (t & 63) * 4;
    float4* a = (float4*)&pA[row][c4];
    float4 bv = *(float4*)&pB[row][c4];
    float4 av = *a;
    av.x += bv.x; av.y += bv.y; av.z += bv.z; av.w += bv.w;
    *a = av;
  };

  if (kc == 0) writeT(pA);
  if (kc == 1) writeT(pB);
  __syncthreads();
  addB2A();
  __syncthreads();
  if (kc == 2) writeT(pB);
  __syncthreads();
  addB2A();
  __syncthreads();
  if (kc == 3) writeT(pB);
  __syncthreads();
  addB2A();
  __syncthreads();

  if (t < 64) {  // s1/s2
    const int r = t & 15, hh = t >> 4;
    float s1 = 0.f, s2 = 0.f;
    for (int d = 0; d < HD; ++d) {
      float v = pA[r][hh * 64 + d];
      s1 += v * attnL[hh * 128 + d];
      s2 += v * attnL[hh * 128 + 64 + d];
    }
    s1g[hh * L_ + i0 + r] = s1;
    s2g[hh * L_ + i0 + r] = s2;
  }

  if (t < 256) {  // WhTf store: thread t = d; two 16B writes
    const int d = t;
    const int hd = d >> 6, nt = (d >> 4) & 3, dc0 = d & 15;
    const int jblock = i0 >> 5, qbase = (i0 & 31) >> 3;
    u16* base = WhTf + ((size_t)(hd * 4 + nt) * JW + jblock) * 512 + dc0 * 8;
    #pragma unroll
    for (int jh = 0; jh < 2; ++jh) {
      const int i = jh * 8;
      union { unsigned u[4]; int4 v; } pk;
      pk.u[0] = cvt2(pA[i + 0][d], pA[i + 1][d]);
      pk.u[1] = cvt2(pA[i + 2][d], pA[i + 3][d]);
      pk.u[2] = cvt2(pA[i + 4][d], pA[i + 5][d]);
      pk.u[3] = cvt2(pA[i + 6][d], pA[i + 7][d]);
      *(int4*)(base + (qbase + jh) * 128) = pk.v;
    }
  }
}

// ---------------------------------------------------------------------------
// K2: [A-rows -> LDS bitmask prologue, coalesced] + masked softmax + PV +
// fused projection. Block 1024 = 16 waves (hd = wv&3, jc = wv>>2).
// Hot loop: WhTf coalesced chunks, s2 quad-broadcast, mask from LDS.
// ---------------------------------------------------------------------------
__global__ __launch_bounds__(1024) void k2_attn(
    const int* __restrict__ A, const u16* __restrict__ WhTf,
    const float* __restrict__ s1g, const float* __restrict__ s2g,
    const float* __restrict__ out_w, const float* __restrict__ out_b,
    float* __restrict__ out)
{
  const int i0 = blockIdx.x * 16;
  const int t = threadIdx.x;
  const int wv = t >> 6, lane = t & 63, q = lane >> 4, c0 = lane & 15;
  const int hd = wv & 3, jc = wv >> 2;
  int rowm[4], colm[4];
  mfma_cdmap(lane, rowm, colm);

  __shared__ float pA[NH][16][HD + 4];
  __shared__ float pB[NH][16][HD + 4];
  __shared__ float dden[NH][4][16];
  __shared__ float rcpS[NH][16];
  __shared__ u16  CnL[16][DOUT + 8];
  __shared__ unsigned AbitL[16][JW + 2];   // row-stride 130 -> varied banks

  {  // prologue: pack this block's 16 A-rows -> bitmask (coalesced reads)
    const int row = t >> 6, ln = t & 63;
    const int* Ar = A + (size_t)(i0 + row) * L_;
    #pragma unroll
    for (int wsel = 0; wsel < 2; ++wsel) {
      const int wI = ln * 2 + wsel;
      const int* p = Ar + wI * 32;
      unsigned bits = 0u;
      #pragma unroll
      for (int wd = 0; wd < 8; ++wd) {
        int4 v = *(const int4*)(p + wd * 4);
        bits |= (v.x > 0 ? 1u : 0u) << (wd * 4 + 0);
        bits |= (v.y > 0 ? 1u : 0u) << (wd * 4 + 1);
        bits |= (v.z > 0 ? 1u : 0u) << (wd * 4 + 2);
        bits |= (v.w > 0 ? 1u : 0u) << (wd * 4 + 3);
      }
      AbitL[row][wI] = bits;
    }
  }
  __syncthreads();

  const float s1v = s1g[hd * L_ + i0 + c0];
  const float* s2h = s2g + (size_t)hd * L_;
  const u16* Wc = WhTf + (size_t)(hd * 4) * JW * 512 + (size_t)(jc * 32) * 512 + lane * 8;

  floatx4 acc[4] = {};
  float dpart = 0.f;
  const int jbase = jc * 1024;

  for (int kt = 0; kt < 32; ++kt) {
    const int kb = jbase + kt * 32 + q * 8;
    float4 sa = *(const float4*)(s2h + kb);
    float4 sb = *(const float4*)(s2h + kb + 4);
    const float sv[8] = {sa.x, sa.y, sa.z, sa.w, sb.x, sb.y, sb.z, sb.w};
    const unsigned mbits = (AbitL[c0][jc * 32 + kt] >> (q * 8)) & 0xffu;
    float ex[8];
    #pragma unroll
    for (int jj = 0; jj < 8; ++jj) {
      float e = s1v + sv[jj];
      e = fmaxf(e, 0.2f * e);                       // leaky_relu 0.2
      float x = __expf(e);
      ex[jj] = ((mbits >> jj) & 1u) ? x : 0.f;      // mask = (A > 0)
      dpart += ex[jj];
    }
    union { unsigned u[4]; short8 s; } pf;          // P A-frag [m=c0][k=j]
    pf.u[0] = cvt2(ex[0], ex[1]); pf.u[1] = cvt2(ex[2], ex[3]);
    pf.u[2] = cvt2(ex[4], ex[5]); pf.u[3] = cvt2(ex[6], ex[7]);
    #pragma unroll
    for (int nt = 0; nt < 4; ++nt) {                // coalesced 1KB chunk loads
      short8 bfr = *(const short8*)(Wc + ((size_t)nt * JW + kt) * 512);
      acc[nt] = __builtin_amdgcn_mfma_f32_16x16x32_bf16(pf.s, bfr, acc[nt], 0, 0, 0);
    }
  }

  // partial denom of row c0 over this j-chunk
  dpart += __shfl_xor(dpart, 16, 64);
  dpart += __shfl_xor(dpart, 32, 64);
  if (lane < 16) dden[hd][jc][lane] = dpart;

  auto writeT = [&](float (*P)[HD + 4]) {
    #pragma unroll
    for (int nt = 0; nt < 4; ++nt)
      #pragma unroll
      for (int r = 0; r < 4; ++r)
        P[rowm[r]][nt * 16 + colm[r]] = acc[nt][r];
  };
  auto addB2A = [&]() {
    const int h2 = t >> 8, rem = t & 255, row = rem >> 4, d4 = (rem & 15) * 4;
    float4* a = (float4*)&pA[h2][row][d4];
    float4 bv = *(float4*)&pB[h2][row][d4];
    float4 av = *a;
    av.x += bv.x; av.y += bv.y; av.z += bv.z; av.w += bv.w;
    *a = av;
  };

  if (jc == 0) writeT(pA[hd]);
  if (jc == 1) writeT(pB[hd]);
  __syncthreads();
  if (t < 64) {
    const int hh = t >> 4, r = t & 15;
    float den = dden[hh][0][r] + dden[hh][1][r] + dden[hh][2][r] + dden[hh][3][r];
    rcpS[hh][r] = (den > 0.f) ? (1.f / den) : 0.f;  // empty row -> out = bias
  }
  addB2A();
  __syncthreads();
  if (jc == 2) writeT(pB[hd]);
  __syncthreads();
  addB2A();
  __syncthreads();
  if (jc == 3) writeT(pB[hd]);
  __syncthreads();
  addB2A();
  __syncthreads();

  {  // Cn (bf16)
    const int row = t >> 6, c4 = (t & 63) * 4;
    #pragma unroll
    for (int x = 0; x < 4; ++x) {
      const int col = c4 + x;
      const int hh = col >> 6, d = col & 63;
      CnL[row][col] = f2bf(pA[hh][row][d] * rcpS[hh][row]);
    }
  }
  __syncthreads();

  if (wv < 4) {  // projection: Out2(16x256) = Cn @ out_w.T
    const int cg = wv;
    floatx4 o[4] = {};
    #pragma unroll
    for (int kt = 0; kt < DOUT / 32; ++kt) {
      const int kb2 = kt * 32 + q * 8;
      short8 afr = *(const short8*)(&CnL[c0][kb2]);
      #pragma unroll
      for (int nt = 0; nt < 4; ++nt) {
        const int col = cg * 64 + nt * 16 + c0;
        short8 bfo = pack8(out_w + (size_t)col * DOUT + kb2);
        o[nt] = __builtin_amdgcn_mfma_f32_16x16x32_bf16(afr, bfo, o[nt], 0, 0, 0);
      }
    }
    #pragma unroll
    for (int nt = 0; nt < 4; ++nt)
      #pragma unroll
      for (int r = 0; r < 4; ++r) {
        const int col = cg * 64 + nt * 16 + colm[r];
        out[(size_t)(i0 + rowm[r]) * DOUT + col] = o[nt][r] + out_b[col];
      }
  }
}

// ---------------------------------------------------------------------------
extern "C" void kernel_launch(void* const* d_in, const int* in_sizes, int n_in,
                              void* d_out, int out_size, void* d_ws, size_t ws_size,
                              hipStream_t stream) {
  const float* h     = (const float*)d_in[0];   // (4096, 512) fp32
  const int*   A     = (const int*)d_in[1];     // (4096, 4096) int32
  const float* W     = (const float*)d_in[2];   // (256, 512) fp32
  const float* attn  = (const float*)d_in[3];   // (4, 128) fp32
  const float* out_w = (const float*)d_in[4];   // (256, 256) fp32
  const float* out_b = (const float*)d_in[5];   // (256,) fp32
  float* outp = (float*)d_out;                  // (4096, 256) fp32

  // ws: WhTf bf16 (2 MB) | s1 f32 | s2 f32   (proven floor, r6+)
  u16*   WhTf = (u16*)d_ws;
  float* s1g  = (float*)((char*)d_ws + (size_t)DOUT * L_ * 2);
  float* s2g  = s1g + NH * L_;
  // Wf lives in d_out (k0b -> k1 -> k2 serialize; k2 overwrites d_out last)
  u16* Wf = (u16*)d_out;

  hipLaunchKernelGGL(k0b_wf, dim3(16), dim3(256), 0, stream, W, Wf);
  hipLaunchKernelGGL(k1_wh, dim3(L_ / 16), dim3(1024), 0, stream,
                     h, Wf, attn, WhTf, s1g, s2g);
  hipLaunchKernelGGL(k2_attn, dim3(L_ / 16), dim3(1024), 0, stream,
                     A, WhTf, s1g, s2g, out_w, out_b, outp);
}